// Round 2
// baseline (750.247 us; speedup 1.0000x reference)
//
#include <hip/hip_runtime.h>
#include <hip/hip_bf16.h>

#define D_FEAT 32

// ---------------------------------------------------------------------------
// K0a: write L2-normalized feature rows into norm_feat (8 lanes per node,
// float4). Used when workspace is big enough.
// ---------------------------------------------------------------------------
__global__ void node_norm_feat_kernel(const float* __restrict__ feat,
                                      float* __restrict__ norm_feat,
                                      int n_nodes) {
    int g = blockIdx.x * blockDim.x + threadIdx.x;
    int node = g >> 3;
    int lane = g & 7;
    if (node >= n_nodes) return;
    float4 v = reinterpret_cast<const float4*>(feat + (size_t)node * D_FEAT)[lane];
    float ss = v.x * v.x + v.y * v.y + v.z * v.z + v.w * v.w;
    #pragma unroll
    for (int m = 4; m; m >>= 1) ss += __shfl_xor(ss, m, 8);
    float inv = 1.0f / fmaxf(sqrtf(ss), 1e-12f);
    v.x *= inv; v.y *= inv; v.z *= inv; v.w *= inv;
    reinterpret_cast<float4*>(norm_feat + (size_t)node * D_FEAT)[lane] = v;
}

// ---------------------------------------------------------------------------
// K0b: fallback — per-node inverse norms only (small ws).
// ---------------------------------------------------------------------------
__global__ void node_invnorm_kernel(const float* __restrict__ feat,
                                    float* __restrict__ inv_norm, int n_nodes) {
    int g = blockIdx.x * blockDim.x + threadIdx.x;
    int node = g >> 3;
    int lane = g & 7;
    if (node >= n_nodes) return;
    float4 v = reinterpret_cast<const float4*>(feat + (size_t)node * D_FEAT)[lane];
    float ss = v.x * v.x + v.y * v.y + v.z * v.z + v.w * v.w;
    #pragma unroll
    for (int m = 4; m; m >>= 1) ss += __shfl_xor(ss, m, 8);
    if (lane == 0) inv_norm[node] = 1.0f / fmaxf(sqrtf(ss), 1e-12f);
}

// ---------------------------------------------------------------------------
// K1: per-edge p_e = exp(beta * cos(u,v)); atomic segment-sum into s[dst].
//     8 lanes per edge, float4 row reads (128B coalesced per row).
//     PRENORM: nf holds normalized rows. else: nf=feat, scale by inv_norm.
// ---------------------------------------------------------------------------
template <bool PRENORM>
__global__ void edge_p_kernel(const float* __restrict__ nf,
                              const float* __restrict__ inv_norm,
                              const int* __restrict__ src,
                              const int* __restrict__ dst,
                              const float* __restrict__ beta,
                              float* __restrict__ p,
                              float* __restrict__ s,
                              int n_edges) {
    int g = blockIdx.x * blockDim.x + threadIdx.x;
    int e = g >> 3;
    int lane = g & 7;
    if (e >= n_edges) return;
    int u = src[e];
    int v = dst[e];
    float4 a = reinterpret_cast<const float4*>(nf + (size_t)u * D_FEAT)[lane];
    float4 b = reinterpret_cast<const float4*>(nf + (size_t)v * D_FEAT)[lane];
    float d = a.x * b.x;
    d = fmaf(a.y, b.y, d);
    d = fmaf(a.z, b.z, d);
    d = fmaf(a.w, b.w, d);
    #pragma unroll
    for (int m = 4; m; m >>= 1) d += __shfl_xor(d, m, 8);
    if (lane == 0) {
        float e_val = beta[0] * d;
        if (!PRENORM) e_val *= inv_norm[u] * inv_norm[v];
        float pe = __expf(e_val);  // |e| <= beta: no overflow, max-shift skipped
        p[e] = pe;
        atomicAdd(&s[v], pe);
    }
}

// ---------------------------------------------------------------------------
// K2: out[dst] += feat[src] * (p_e / s[dst]); 8 lanes/edge, 4 atomics/lane.
// ---------------------------------------------------------------------------
__global__ void aggregate_kernel(const float* __restrict__ feat,
                                 const int* __restrict__ src,
                                 const int* __restrict__ dst,
                                 const float* __restrict__ p,
                                 const float* __restrict__ s,
                                 float* __restrict__ out,
                                 int n_edges) {
    int g = blockIdx.x * blockDim.x + threadIdx.x;
    int e = g >> 3;
    int lane = g & 7;
    if (e >= n_edges) return;
    int u = src[e];
    int v = dst[e];
    float w = p[e] / s[v];
    float4 a = reinterpret_cast<const float4*>(feat + (size_t)u * D_FEAT)[lane];
    float* o = out + (size_t)v * D_FEAT + lane * 4;
    atomicAdd(o + 0, a.x * w);
    atomicAdd(o + 1, a.y * w);
    atomicAdd(o + 2, a.z * w);
    atomicAdd(o + 3, a.w * w);
}

extern "C" void kernel_launch(void* const* d_in, const int* in_sizes, int n_in,
                              void* d_out, int out_size, void* d_ws, size_t ws_size,
                              hipStream_t stream) {
    const float* feat = (const float*)d_in[0];
    const float* beta = (const float*)d_in[1];
    const int*   src  = (const int*)d_in[2];
    const int*   dst  = (const int*)d_in[3];
    float* out = (float*)d_out;

    int n_nodes = in_sizes[0] / D_FEAT;
    int n_edges = in_sizes[2];

    size_t need_full = ((size_t)n_nodes * D_FEAT + n_nodes + n_edges) * sizeof(float);
    bool prenorm = ws_size >= need_full;

    float* base = (float*)d_ws;
    float* norm_feat = nullptr;  // [n_nodes*D] (prenorm path)
    float* inv_norm  = nullptr;  // [n_nodes]   (fallback path)
    float* s_sum;
    float* p;
    if (prenorm) {
        norm_feat = base;
        s_sum = norm_feat + (size_t)n_nodes * D_FEAT;
    } else {
        inv_norm = base;
        s_sum = inv_norm + n_nodes;
    }
    p = s_sum + n_nodes;

    hipMemsetAsync(s_sum, 0, (size_t)n_nodes * sizeof(float), stream);
    hipMemsetAsync(out, 0, (size_t)out_size * sizeof(float), stream);

    {
        int total = n_nodes * 8;
        int blocks = (total + 255) / 256;
        if (prenorm)
            node_norm_feat_kernel<<<blocks, 256, 0, stream>>>(feat, norm_feat, n_nodes);
        else
            node_invnorm_kernel<<<blocks, 256, 0, stream>>>(feat, inv_norm, n_nodes);
    }
    {
        long long total = (long long)n_edges * 8;
        int blocks = (int)((total + 255) / 256);
        if (prenorm)
            edge_p_kernel<true><<<blocks, 256, 0, stream>>>(norm_feat, nullptr, src, dst,
                                                            beta, p, s_sum, n_edges);
        else
            edge_p_kernel<false><<<blocks, 256, 0, stream>>>(feat, inv_norm, src, dst,
                                                             beta, p, s_sum, n_edges);
    }
    {
        long long total = (long long)n_edges * 8;
        int blocks = (int)((total + 255) / 256);
        aggregate_kernel<<<blocks, 256, 0, stream>>>(feat, src, dst, p, s_sum,
                                                     out, n_edges);
    }
}

// Round 3
// 231.432 us; speedup vs baseline: 3.2418x; 3.2418x over previous
//
#include <hip/hip_runtime.h>
#include <hip/hip_bf16.h>

#define D_FEAT 32
#define SCAN_BLOCK 512

// ---------------------------------------------------------------------------
// K0: per-node inverse L2 norm (8 lanes/node, float4 loads).
// ---------------------------------------------------------------------------
__global__ void node_invnorm_kernel(const float* __restrict__ feat,
                                    float* __restrict__ inv_norm, int n_nodes) {
    int g = blockIdx.x * blockDim.x + threadIdx.x;
    int node = g >> 3;
    int lane = g & 7;
    if (node >= n_nodes) return;
    float4 v = reinterpret_cast<const float4*>(feat + (size_t)node * D_FEAT)[lane];
    float ss = v.x * v.x + v.y * v.y + v.z * v.z + v.w * v.w;
    #pragma unroll
    for (int m = 4; m; m >>= 1) ss += __shfl_xor(ss, m, 8);
    if (lane == 0) inv_norm[node] = 1.0f / fmaxf(sqrtf(ss), 1e-12f);
}

// ---------------------------------------------------------------------------
// K1: in-degree count.
// ---------------------------------------------------------------------------
__global__ void degree_kernel(const int* __restrict__ dst, int* __restrict__ deg,
                              int n_edges) {
    int i = blockIdx.x * blockDim.x + threadIdx.x;
    if (i < n_edges) atomicAdd(&deg[dst[i]], 1);
}

// ---------------------------------------------------------------------------
// Scan S1: per-block exclusive scan of deg; block totals to block_sums.
// ---------------------------------------------------------------------------
__global__ void scan_blocks_kernel(const int* __restrict__ deg,
                                   int* __restrict__ row_ptr,
                                   int* __restrict__ block_sums, int n) {
    __shared__ int tmp[SCAN_BLOCK];
    int i = blockIdx.x * SCAN_BLOCK + threadIdx.x;
    int v = (i < n) ? deg[i] : 0;
    tmp[threadIdx.x] = v;
    __syncthreads();
    for (int off = 1; off < SCAN_BLOCK; off <<= 1) {
        int add = (threadIdx.x >= (unsigned)off) ? tmp[threadIdx.x - off] : 0;
        __syncthreads();
        tmp[threadIdx.x] += add;
        __syncthreads();
    }
    if (i < n) row_ptr[i] = tmp[threadIdx.x] - v;  // local exclusive
    if (threadIdx.x == SCAN_BLOCK - 1) block_sums[blockIdx.x] = tmp[threadIdx.x];
}

// ---------------------------------------------------------------------------
// Scan S2: single-block exclusive scan of block_sums (nb <= 1024).
// ---------------------------------------------------------------------------
__global__ void scan_partials_kernel(int* __restrict__ block_sums, int nb) {
    __shared__ int tmp[1024];
    int t = threadIdx.x;
    int v = (t < nb) ? block_sums[t] : 0;
    tmp[t] = v;
    __syncthreads();
    for (int off = 1; off < 1024; off <<= 1) {
        int add = (t >= off) ? tmp[t - off] : 0;
        __syncthreads();
        tmp[t] += add;
        __syncthreads();
    }
    if (t < nb) block_sums[t] = tmp[t] - v;  // exclusive offsets
}

// ---------------------------------------------------------------------------
// Scan S3: add block offsets; emit final row_ptr and cursor copy.
// ---------------------------------------------------------------------------
__global__ void scan_finalize_kernel(int* __restrict__ row_ptr,
                                     int* __restrict__ cursor,
                                     const int* __restrict__ block_sums,
                                     int n, int n_edges) {
    int i = blockIdx.x * blockDim.x + threadIdx.x;
    if (i < n) {
        int r = row_ptr[i] + block_sums[i / SCAN_BLOCK];
        row_ptr[i] = r;
        cursor[i] = r;
    }
    if (i == n) row_ptr[n] = n_edges;
}

// ---------------------------------------------------------------------------
// K2: per-edge p_e = exp(beta*cos) scattered into CSR slots (8 lanes/edge).
// ---------------------------------------------------------------------------
__global__ void edge_scatter_kernel(const float* __restrict__ feat,
                                    const float* __restrict__ inv_norm,
                                    const int* __restrict__ src,
                                    const int* __restrict__ dst,
                                    const float* __restrict__ beta,
                                    int* __restrict__ cursor,
                                    int* __restrict__ csr_src,
                                    float* __restrict__ csr_p,
                                    int n_edges) {
    int g = blockIdx.x * blockDim.x + threadIdx.x;
    int e = g >> 3;
    int lane = g & 7;
    if (e >= n_edges) return;
    int u = src[e];
    int v = dst[e];
    float4 a = reinterpret_cast<const float4*>(feat + (size_t)u * D_FEAT)[lane];
    float4 b = reinterpret_cast<const float4*>(feat + (size_t)v * D_FEAT)[lane];
    float d = a.x * b.x;
    d = fmaf(a.y, b.y, d);
    d = fmaf(a.z, b.z, d);
    d = fmaf(a.w, b.w, d);
    #pragma unroll
    for (int m = 4; m; m >>= 1) d += __shfl_xor(d, m, 8);
    if (lane == 0) {
        float e_val = beta[0] * d * inv_norm[u] * inv_norm[v];
        float pe = __expf(e_val);  // |e| <= beta; softmax max-shift unnecessary
        int pos = atomicAdd(&cursor[v], 1);
        csr_src[pos] = u;
        csr_p[pos] = pe;
    }
}

// ---------------------------------------------------------------------------
// K3: per-node gather-reduce. out[n] = (sum_e p_e * feat[src_e]) / sum_e p_e.
//     8 lanes per node; single coalesced float4 row write; NO atomics.
// ---------------------------------------------------------------------------
__global__ void gather_out_kernel(const float* __restrict__ feat,
                                  const int* __restrict__ row_ptr,
                                  const int* __restrict__ csr_src,
                                  const float* __restrict__ csr_p,
                                  float* __restrict__ out, int n_nodes) {
    int g = blockIdx.x * blockDim.x + threadIdx.x;
    int node = g >> 3;
    int lane = g & 7;
    if (node >= n_nodes) return;
    int start = row_ptr[node];
    int end   = row_ptr[node + 1];
    float4 acc = make_float4(0.f, 0.f, 0.f, 0.f);
    float ssum = 0.f;
    for (int i = start; i < end; ++i) {
        int u = csr_src[i];      // same addr across 8 lanes -> broadcast
        float pe = csr_p[i];
        float4 a = reinterpret_cast<const float4*>(feat + (size_t)u * D_FEAT)[lane];
        acc.x = fmaf(pe, a.x, acc.x);
        acc.y = fmaf(pe, a.y, acc.y);
        acc.z = fmaf(pe, a.z, acc.z);
        acc.w = fmaf(pe, a.w, acc.w);
        ssum += pe;
    }
    float inv_s = (end > start) ? (1.0f / ssum) : 0.0f;
    acc.x *= inv_s; acc.y *= inv_s; acc.z *= inv_s; acc.w *= inv_s;
    reinterpret_cast<float4*>(out + (size_t)node * D_FEAT)[lane] = acc;
}

// ---------------------------------------------------------------------------
// Fallback (small ws): proven R1-style atomic path.
// ---------------------------------------------------------------------------
__global__ void edge_p_kernel(const float* __restrict__ feat,
                              const float* __restrict__ inv_norm,
                              const int* __restrict__ src,
                              const int* __restrict__ dst,
                              const float* __restrict__ beta,
                              float* __restrict__ p, float* __restrict__ s,
                              int n_edges) {
    int g = blockIdx.x * blockDim.x + threadIdx.x;
    int e = g >> 3;
    int lane = g & 7;
    if (e >= n_edges) return;
    int u = src[e];
    int v = dst[e];
    float4 a = reinterpret_cast<const float4*>(feat + (size_t)u * D_FEAT)[lane];
    float4 b = reinterpret_cast<const float4*>(feat + (size_t)v * D_FEAT)[lane];
    float d = a.x * b.x;
    d = fmaf(a.y, b.y, d);
    d = fmaf(a.z, b.z, d);
    d = fmaf(a.w, b.w, d);
    #pragma unroll
    for (int m = 4; m; m >>= 1) d += __shfl_xor(d, m, 8);
    if (lane == 0) {
        float pe = __expf(beta[0] * d * inv_norm[u] * inv_norm[v]);
        p[e] = pe;
        atomicAdd(&s[v], pe);
    }
}

__global__ void aggregate_atomic_kernel(const float* __restrict__ feat,
                                        const int* __restrict__ src,
                                        const int* __restrict__ dst,
                                        const float* __restrict__ p,
                                        const float* __restrict__ s,
                                        float* __restrict__ out, int n_edges) {
    int g = blockIdx.x * blockDim.x + threadIdx.x;
    int e = g >> 5;
    int lane = g & 31;
    if (e >= n_edges) return;
    int u = src[e];
    int v = dst[e];
    float w = p[e] / s[v];
    atomicAdd(&out[(size_t)v * D_FEAT + lane], feat[(size_t)u * D_FEAT + lane] * w);
}

extern "C" void kernel_launch(void* const* d_in, const int* in_sizes, int n_in,
                              void* d_out, int out_size, void* d_ws, size_t ws_size,
                              hipStream_t stream) {
    const float* feat = (const float*)d_in[0];
    const float* beta = (const float*)d_in[1];
    const int*   src  = (const int*)d_in[2];
    const int*   dst  = (const int*)d_in[3];
    float* out = (float*)d_out;

    int n_nodes = in_sizes[0] / D_FEAT;
    int n_edges = in_sizes[2];
    int nb = (n_nodes + SCAN_BLOCK - 1) / SCAN_BLOCK;

    // CSR-path workspace layout (all 4B elements):
    // inv_norm[N] | row_ptr[N+1] | cursor[N] | block_sums[1024] | csr_src[E] | csr_p[E]
    size_t need_csr = ((size_t)n_nodes * 3 + 1 + 1024 + (size_t)n_edges * 2) * 4;
    bool use_csr = (ws_size >= need_csr) && (nb <= 1024);

    if (use_csr) {
        float* inv_norm = (float*)d_ws;
        int* row_ptr    = (int*)(inv_norm + n_nodes);       // used as deg first
        int* cursor     = row_ptr + (n_nodes + 1);
        int* block_sums = cursor + n_nodes;
        int* csr_src    = block_sums + 1024;
        float* csr_p    = (float*)(csr_src + n_edges);

        hipMemsetAsync(row_ptr, 0, (size_t)(n_nodes + 1) * sizeof(int), stream);

        {
            int total = n_nodes * 8;
            node_invnorm_kernel<<<(total + 255) / 256, 256, 0, stream>>>(feat, inv_norm, n_nodes);
        }
        degree_kernel<<<(n_edges + 255) / 256, 256, 0, stream>>>(dst, row_ptr, n_edges);
        // exclusive scan of deg -> row_ptr (in place) + cursor
        scan_blocks_kernel<<<nb, SCAN_BLOCK, 0, stream>>>(row_ptr, row_ptr, block_sums, n_nodes);
        scan_partials_kernel<<<1, 1024, 0, stream>>>(block_sums, nb);
        scan_finalize_kernel<<<(n_nodes + 1 + 255) / 256, 256, 0, stream>>>(
            row_ptr, cursor, block_sums, n_nodes, n_edges);
        {
            long long total = (long long)n_edges * 8;
            edge_scatter_kernel<<<(int)((total + 255) / 256), 256, 0, stream>>>(
                feat, inv_norm, src, dst, beta, cursor, csr_src, csr_p, n_edges);
        }
        {
            int total = n_nodes * 8;
            gather_out_kernel<<<(total + 255) / 256, 256, 0, stream>>>(
                feat, row_ptr, csr_src, csr_p, out, n_nodes);
        }
    } else {
        // Fallback: atomic path (R1 layout).
        float* inv_norm = (float*)d_ws;
        float* s_sum    = inv_norm + n_nodes;
        float* p        = s_sum + n_nodes;

        hipMemsetAsync(s_sum, 0, (size_t)n_nodes * sizeof(float), stream);
        hipMemsetAsync(out, 0, (size_t)out_size * sizeof(float), stream);

        {
            int total = n_nodes * 8;
            node_invnorm_kernel<<<(total + 255) / 256, 256, 0, stream>>>(feat, inv_norm, n_nodes);
        }
        {
            long long total = (long long)n_edges * 8;
            edge_p_kernel<<<(int)((total + 255) / 256), 256, 0, stream>>>(
                feat, inv_norm, src, dst, beta, p, s_sum, n_edges);
        }
        {
            long long total = (long long)n_edges * 32;
            aggregate_atomic_kernel<<<(int)((total + 255) / 256), 256, 0, stream>>>(
                feat, src, dst, p, s_sum, out, n_edges);
        }
    }
}